// Round 1
// baseline (602.302 us; speedup 1.0000x reference)
//
#include <hip/hip_runtime.h>
#include <stdint.h>

#define N_NODES 6144
#define F_IN 512
#define NHEAD 4
#define FH 64
#define HF 256   // NHEAD*FH
#define NCLS 40
#define CAP 192
#define LRELU_ALPHA 0.2f
#define NB 512          // persistent grid: 2 blocks/CU x 256 CUs, co-resident by __launch_bounds__(256,2)
#define NITEMS_A 6577   // 384 gemm1 tiles + 48 Wo-prep + 1 zero + 6144 adj rows

typedef __bf16 bf16x8 __attribute__((ext_vector_type(8)));
typedef float floatx4 __attribute__((ext_vector_type(4)));
typedef uint16_t u16x8 __attribute__((ext_vector_type(8)));

__device__ __forceinline__ float b2f(uint16_t u){
    union { float f; uint32_t i; } x; x.i = ((uint32_t)u) << 16; return x.f;
}
__device__ __forceinline__ uint16_t f2b(float f){
    union { float f; uint32_t i; } x; x.f = f;
    uint32_t r = x.i + 0x7FFFu + ((x.i >> 16) & 1u);
    return (uint16_t)(r >> 16);
}
__device__ __forceinline__ void cvt_split8(const float* __restrict__ s, bf16x8& hv, bf16x8& lv){
    union { u16x8 u; bf16x8 b; } H, L;
    #pragma unroll
    for (int j = 0; j < 8; j++){
        uint16_t hb = f2b(s[j]);
        H.u[j] = hb;
        L.u[j] = f2b(s[j] - b2f(hb));
    }
    hv = H.b; lv = L.b;
}

// Device-scope grid barrier (monotonic counter). All NB blocks are guaranteed
// co-resident (launch_bounds(256,2) => 2 blocks/CU min => capacity 512).
// Release fence + agent-scope atomic + acquire fence = the ROCm cooperative
// grid.sync pattern (G16: cross-XCD visibility needs device-scope fences).
__device__ __forceinline__ void gsync(int* bar, int target){
    __syncthreads();
    if (threadIdx.x == 0){
        __threadfence();
        __hip_atomic_fetch_add(bar, 1, __ATOMIC_RELEASE, __HIP_MEMORY_SCOPE_AGENT);
        while (__hip_atomic_load(bar, __ATOMIC_ACQUIRE, __HIP_MEMORY_SCOPE_AGENT) < target)
            __builtin_amdgcn_s_sleep(1);
        __threadfence();
    }
    __syncthreads();
}

__global__ __launch_bounds__(256, 2) void k_fused(
    const float* __restrict__ adj, const float* __restrict__ x,
    const float* __restrict__ W,   const float* __restrict__ Wo,
    const float* __restrict__ a1,  const float* __restrict__ a2,
    const float* __restrict__ ao1, const float* __restrict__ ao2,
    int* __restrict__ cnt, int* __restrict__ idxbuf,
    uint16_t* __restrict__ Woth, uint16_t* __restrict__ Wotl,
    uint16_t* __restrict__ Wh1b, float* __restrict__ f1, float* __restrict__ f2,
    uint16_t* __restrict__ hch, uint16_t* __restrict__ hcl,
    float* __restrict__ Wh2, float* __restrict__ f1o, float* __restrict__ f2o,
    float* __restrict__ out, int* __restrict__ bar)
{
    const int t = threadIdx.x;
    __shared__ float sred[2][2][64];
    __shared__ int   scnt;
    __shared__ int   sidxB[CAP];
    __shared__ float spB[NHEAD][CAP];
    __shared__ int   sidxD[4][CAP];
    __shared__ float spD[4][CAP];

    // ================= Stage A: gemm1 + Wo prep + zero + adj scan =================
    for (int b = blockIdx.x; b < NITEMS_A; b += NB){
        if (b < 384){
            // ---- gemm1: Wh1b = bf16(x @ W_head), fused f1/f2 ----
            int w = t >> 6, l = t & 63;
            int bx = b >> 2, h = b & 3;
            int m = l & 15, q = l >> 4;
            int rt0 = bx * 4 + (w & 1) * 2;
            int ctl = (w >> 1) * 2;
            const float* pa0 = x + (size_t)(rt0 * 16 + m) * F_IN + q * 8;
            const float* pa1 = pa0 + 16 * F_IN;
            const float* pb = W + h * 32768 + q * 8 * 64 + ctl * 16 + m;
            floatx4 acc[2][2] = {};
            for (int kc = 0; kc < 16; kc++){
                float av0[8], av1[8], bv0[8], bv1[8];
                *reinterpret_cast<float4*>(av0)     = *reinterpret_cast<const float4*>(pa0 + kc * 32);
                *reinterpret_cast<float4*>(av0 + 4) = *reinterpret_cast<const float4*>(pa0 + kc * 32 + 4);
                *reinterpret_cast<float4*>(av1)     = *reinterpret_cast<const float4*>(pa1 + kc * 32);
                *reinterpret_cast<float4*>(av1 + 4) = *reinterpret_cast<const float4*>(pa1 + kc * 32 + 4);
                const float* pbk = pb + kc * 2048;
                #pragma unroll
                for (int j = 0; j < 8; j++){
                    bv0[j] = pbk[j * 64];
                    bv1[j] = pbk[j * 64 + 16];
                }
                bf16x8 a0h, a0l, a1h_, a1l_, b0h, b0l, b1h, b1l;
                cvt_split8(av0, a0h, a0l);
                cvt_split8(av1, a1h_, a1l_);
                cvt_split8(bv0, b0h, b0l);
                cvt_split8(bv1, b1h, b1l);
                acc[0][0] = __builtin_amdgcn_mfma_f32_16x16x32_bf16(a0h, b0l, acc[0][0], 0, 0, 0);
                acc[0][0] = __builtin_amdgcn_mfma_f32_16x16x32_bf16(a0l, b0h, acc[0][0], 0, 0, 0);
                acc[0][0] = __builtin_amdgcn_mfma_f32_16x16x32_bf16(a0h, b0h, acc[0][0], 0, 0, 0);
                acc[0][1] = __builtin_amdgcn_mfma_f32_16x16x32_bf16(a0h, b1l, acc[0][1], 0, 0, 0);
                acc[0][1] = __builtin_amdgcn_mfma_f32_16x16x32_bf16(a0l, b1h, acc[0][1], 0, 0, 0);
                acc[0][1] = __builtin_amdgcn_mfma_f32_16x16x32_bf16(a0h, b1h, acc[0][1], 0, 0, 0);
                acc[1][0] = __builtin_amdgcn_mfma_f32_16x16x32_bf16(a1h_, b0l, acc[1][0], 0, 0, 0);
                acc[1][0] = __builtin_amdgcn_mfma_f32_16x16x32_bf16(a1l_, b0h, acc[1][0], 0, 0, 0);
                acc[1][0] = __builtin_amdgcn_mfma_f32_16x16x32_bf16(a1h_, b0h, acc[1][0], 0, 0, 0);
                acc[1][1] = __builtin_amdgcn_mfma_f32_16x16x32_bf16(a1h_, b1l, acc[1][1], 0, 0, 0);
                acc[1][1] = __builtin_amdgcn_mfma_f32_16x16x32_bf16(a1l_, b1h, acc[1][1], 0, 0, 0);
                acc[1][1] = __builtin_amdgcn_mfma_f32_16x16x32_bf16(a1h_, b1h, acc[1][1], 0, 0, 0);
            }
            #pragma unroll
            for (int fr = 0; fr < 2; fr++){
                #pragma unroll
                for (int fc = 0; fc < 2; fc++){
                    int col = h * 64 + (ctl + fc) * 16 + m;
                    int rowb = (rt0 + fr) * 16 + q * 4;
                    #pragma unroll
                    for (int r = 0; r < 4; r++)
                        Wh1b[(size_t)(rowb + r) * HF + col] = f2b(acc[fr][fc][r]);
                }
            }
            float a1v0 = a1[h * FH + (ctl + 0) * 16 + m];
            float a1v1 = a1[h * FH + (ctl + 1) * 16 + m];
            float a2v0 = a2[h * FH + (ctl + 0) * 16 + m];
            float a2v1 = a2[h * FH + (ctl + 1) * 16 + m];
            #pragma unroll
            for (int fr = 0; fr < 2; fr++){
                #pragma unroll
                for (int r = 0; r < 4; r++){
                    float s1 = acc[fr][0][r] * a1v0 + acc[fr][1][r] * a1v1;
                    float s2 = acc[fr][0][r] * a2v0 + acc[fr][1][r] * a2v1;
                    #pragma unroll
                    for (int off = 1; off < 16; off <<= 1){
                        s1 += __shfl_xor(s1, off);
                        s2 += __shfl_xor(s2, off);
                    }
                    if (m == 0){
                        int lr = ((w & 1) * 2 + fr) * 16 + q * 4 + r;
                        sred[w >> 1][0][lr] = s1;
                        sred[w >> 1][1][lr] = s2;
                    }
                }
            }
            __syncthreads();
            if (t < 64){
                int n = bx * 64 + t;
                f1[h * N_NODES + n] = sred[0][0][t] + sred[1][0][t];
                f2[h * N_NODES + n] = sred[0][1][t] + sred[1][1][t];
            }
        } else if (b < 432){
            int T = (b - 384) * 256 + t;          // 0..12287
            int c = T >> 8, k = T & 255;
            float v = (c < NCLS) ? Wo[k * NCLS + c] : 0.f;
            uint16_t hi = f2b(v);
            Woth[c * HF + k] = hi;
            Wotl[c * HF + k] = f2b(v - b2f(hi));
        } else if (b == 432){
            for (int i = t; i < N_NODES; i += 256){ f1o[i] = 0.f; f2o[i] = 0.f; }
        } else {
            // ---- adj row scan -> CSR neighbor list ----
            int i = b - 433;
            if (t == 0) scnt = 0;
            __syncthreads();
            const floatx4* row = reinterpret_cast<const floatx4*>(adj + (size_t)i * N_NODES);
            int* outp = idxbuf + (size_t)i * CAP;
            floatx4 v[6];                         // 1536/256 = 6 exact; all 6 in flight, NT (adj read once)
            #pragma unroll
            for (int u = 0; u < 6; u++)
                v[u] = __builtin_nontemporal_load(row + t + u * 256);
            #pragma unroll
            for (int u = 0; u < 6; u++){
                int j0 = (t + u * 256) * 4;
                if (v[u][0] != 0.f){ int p = atomicAdd(&scnt, 1); if (p < CAP) outp[p] = j0;     }
                if (v[u][1] != 0.f){ int p = atomicAdd(&scnt, 1); if (p < CAP) outp[p] = j0 + 1; }
                if (v[u][2] != 0.f){ int p = atomicAdd(&scnt, 1); if (p < CAP) outp[p] = j0 + 2; }
                if (v[u][3] != 0.f){ int p = atomicAdd(&scnt, 1); if (p < CAP) outp[p] = j0 + 3; }
            }
            __syncthreads();
            if (t == 0) cnt[i] = scnt < CAP ? scnt : CAP;
        }
        __syncthreads();   // protect shared reuse across grid-stride iterations
    }
    gsync(bar, NB);

    // ================= Stage B: layer-1 sparse attention + ELU -> hcat =================
    for (int i = blockIdx.x; i < N_NODES; i += NB){
        int h = t >> 6, l = t & 63;
        int c = cnt[i];
        const int* src = idxbuf + (size_t)i * CAP;
        for (int e = t; e < c; e += 256) sidxB[e] = src[e];
        __syncthreads();
        float f1i = f1[h * N_NODES + i];
        const float* f2h = f2 + h * N_NODES;
        float mx = -1e30f;
        for (int e = l; e < c; e += 64){
            float s = f1i + f2h[sidxB[e]];
            s = s > 0.f ? s : LRELU_ALPHA * s;
            spB[h][e] = s;
            mx = fmaxf(mx, s);
        }
        for (int off = 32; off; off >>= 1) mx = fmaxf(mx, __shfl_xor(mx, off));
        float ssum = 0.f;
        for (int e = l; e < c; e += 64){
            float p = __expf(spB[h][e] - mx);
            spB[h][e] = p;
            ssum += p;
        }
        for (int off = 32; off; off >>= 1) ssum += __shfl_xor(ssum, off);
        float inv = 1.f / ssum;
        float acc = 0.f;
        const uint16_t* whb = Wh1b + h * FH + l;
        int e = 0;
        for (; e + 4 <= c; e += 4){
            int j0 = sidxB[e], j1 = sidxB[e+1], j2 = sidxB[e+2], j3 = sidxB[e+3];
            float v0 = b2f(whb[(size_t)j0 * HF]);
            float v1 = b2f(whb[(size_t)j1 * HF]);
            float v2 = b2f(whb[(size_t)j2 * HF]);
            float v3 = b2f(whb[(size_t)j3 * HF]);
            acc += spB[h][e]*v0 + spB[h][e+1]*v1 + spB[h][e+2]*v2 + spB[h][e+3]*v3;
        }
        for (; e < c; e++)
            acc += spB[h][e] * b2f(whb[(size_t)sidxB[e] * HF]);
        acc *= inv;
        float v = acc > 0.f ? acc : __expf(acc) - 1.f;   // ELU
        uint16_t hi = f2b(v);
        uint16_t lo = f2b(v - b2f(hi));
        size_t o = (size_t)i * HF + h * FH + l;
        hch[o] = hi;
        hcl[o] = lo;
        __syncthreads();   // protect sidxB/spB reuse
    }
    gsync(bar, 2 * NB);

    // ================= Stage C: Wh2 = hcat @ Wo + fused f1o/f2o =================
    // 576 logical 128-thread tiles; 2 tiles per 256-thread block.
    for (int ib = blockIdx.x; ib < 288; ib += NB){
        int T  = ib * 2 + (t >> 7);
        int lt = t & 127;
        int w = lt >> 6, l = lt & 63;
        int bx = T / 3, by = T % 3;
        int r0 = bx * 32 + w * 16;
        int c0 = by * 16;
        int m = l & 15, q = l >> 4;
        const uint16_t* pah = hch  + (size_t)(r0 + m) * HF + q * 8;
        const uint16_t* pal = hcl  + (size_t)(r0 + m) * HF + q * 8;
        const uint16_t* pbh = Woth + (size_t)(c0 + m) * HF + q * 8;
        const uint16_t* pbl = Wotl + (size_t)(c0 + m) * HF + q * 8;
        floatx4 acc = {};
        for (int k0 = 0; k0 < HF; k0 += 32){
            bf16x8 ah = *reinterpret_cast<const bf16x8*>(pah + k0);
            bf16x8 al = *reinterpret_cast<const bf16x8*>(pal + k0);
            bf16x8 bh = *reinterpret_cast<const bf16x8*>(pbh + k0);
            bf16x8 bl = *reinterpret_cast<const bf16x8*>(pbl + k0);
            acc = __builtin_amdgcn_mfma_f32_16x16x32_bf16(ah, bl, acc, 0, 0, 0);
            acc = __builtin_amdgcn_mfma_f32_16x16x32_bf16(al, bh, acc, 0, 0, 0);
            acc = __builtin_amdgcn_mfma_f32_16x16x32_bf16(ah, bh, acc, 0, 0, 0);
        }
        int col = c0 + m;
        bool valid = col < NCLS;
        if (valid){
            int rowb = r0 + q * 4;
            #pragma unroll
            for (int r = 0; r < 4; r++)
                Wh2[(size_t)(rowb + r) * NCLS + col] = acc[r];
        }
        float w1 = valid ? ao1[col] : 0.f;
        float w2 = valid ? ao2[col] : 0.f;
        #pragma unroll
        for (int r = 0; r < 4; r++){
            float s1 = acc[r] * w1;
            float s2 = acc[r] * w2;
            #pragma unroll
            for (int off = 1; off < 16; off <<= 1){
                s1 += __shfl_xor(s1, off);
                s2 += __shfl_xor(s2, off);
            }
            if (m == 0){
                atomicAdd(f1o + r0 + q * 4 + r, s1);
                atomicAdd(f2o + r0 + q * 4 + r, s2);
            }
        }
    }
    gsync(bar, 3 * NB);

    // ================= Stage D: layer-2 attention + ELU + log_softmax =================
    // One node per wave; 4 nodes per block. Wave-synchronous (no block syncs needed).
    for (int ib = blockIdx.x; ib < 1536; ib += NB){
        int w = t >> 6, l = t & 63;
        int i = ib * 4 + w;
        int c = cnt[i];
        int*   sidx = sidxD[w];
        float* sp   = spD[w];
        const int* src = idxbuf + (size_t)i * CAP;
        for (int e = l; e < c; e += 64) sidx[e] = src[e];
        float f1i = f1o[i];
        float mx = -1e30f;
        for (int e = l; e < c; e += 64){
            float s = f1i + f2o[sidx[e]];
            s = s > 0.f ? s : LRELU_ALPHA * s;
            sp[e] = s;
            mx = fmaxf(mx, s);
        }
        for (int off = 32; off; off >>= 1) mx = fmaxf(mx, __shfl_xor(mx, off));
        float ssum = 0.f;
        for (int e = l; e < c; e += 64){
            float p = __expf(sp[e] - mx);
            sp[e] = p;
            ssum += p;
        }
        for (int off = 32; off; off >>= 1) ssum += __shfl_xor(ssum, off);
        float inv = 1.f / ssum;
        float acc = 0.f;
        if (l < NCLS){
            const float* wb = Wh2 + l;
            int e = 0;
            for (; e + 4 <= c; e += 4){
                int j0 = sidx[e], j1 = sidx[e+1], j2 = sidx[e+2], j3 = sidx[e+3];
                float v0 = wb[(size_t)j0 * NCLS];
                float v1 = wb[(size_t)j1 * NCLS];
                float v2 = wb[(size_t)j2 * NCLS];
                float v3 = wb[(size_t)j3 * NCLS];
                acc += sp[e]*v0 + sp[e+1]*v1 + sp[e+2]*v2 + sp[e+3]*v3;
            }
            for (; e < c; e++)
                acc += sp[e] * wb[(size_t)sidx[e] * NCLS];
            acc *= inv;
        }
        float o = (l < NCLS) ? (acc > 0.f ? acc : __expf(acc) - 1.f) : -1e30f;
        float m2 = o;
        for (int off = 32; off; off >>= 1) m2 = fmaxf(m2, __shfl_xor(m2, off));
        float ex = (l < NCLS) ? __expf(o - m2) : 0.f;
        for (int off = 32; off; off >>= 1) ex += __shfl_xor(ex, off);
        float res = o - m2 - logf(ex);
        if (l < NCLS) out[(size_t)i * NCLS + l] = res;
    }
}

extern "C" void kernel_launch(void* const* d_in, const int* in_sizes, int n_in,
                              void* d_out, int out_size, void* d_ws, size_t ws_size,
                              hipStream_t stream) {
    const float* x   = (const float*)d_in[0];
    const float* adj = (const float*)d_in[1];
    const float* W   = (const float*)d_in[2];
    const float* a1  = (const float*)d_in[3];
    const float* a2  = (const float*)d_in[4];
    const float* Wo  = (const float*)d_in[5];
    const float* ao1 = (const float*)d_in[6];
    const float* ao2 = (const float*)d_in[7];
    float* out = (float*)d_out;

    char* ws = (char*)d_ws;
    int*      nbr_cnt = (int*)     (ws + 0);          //     24,576 B
    int*      nbr_idx = (int*)     (ws + 24576);      //  4,718,592 B
    uint16_t* Woth    = (uint16_t*)(ws + 4743168);    //     24,576 B
    uint16_t* Wotl    = (uint16_t*)(ws + 4767744);    //     24,576 B
    uint16_t* Wh1b    = (uint16_t*)(ws + 4792320);    //  3,145,728 B
    float*    f1      = (float*)   (ws + 7938048);    //     98,304 B
    float*    f2      = (float*)   (ws + 8036352);    //     98,304 B
    uint16_t* hch     = (uint16_t*)(ws + 8134656);    //  3,145,728 B
    uint16_t* hcl     = (uint16_t*)(ws + 11280384);   //  3,145,728 B
    float*    Wh2     = (float*)   (ws + 14426112);   //    983,040 B
    float*    f1o     = (float*)   (ws + 15409152);   //     24,576 B
    float*    f2o     = (float*)   (ws + 15433728);   //     24,576 B
    int*      bar     = (int*)     (ws + 15458304);   //         64 B (grid barrier counter)

    hipMemsetAsync(bar, 0, 64, stream);
    hipLaunchKernelGGL(k_fused, dim3(NB), dim3(256), 0, stream,
                       adj, x, W, Wo, a1, a2, ao1, ao2,
                       nbr_cnt, nbr_idx, Woth, Wotl, Wh1b, f1, f2,
                       hch, hcl, Wh2, f1o, f2o, out, bar);
}

// Round 4
// 263.614 us; speedup vs baseline: 2.2848x; 2.2848x over previous
//
#include <hip/hip_runtime.h>
#include <stdint.h>

#define N_NODES 6144
#define F_IN 512
#define NHEAD 4
#define FH 64
#define HF 256   // NHEAD*FH
#define NCLS 40
#define CAP 192
#define LRELU_ALPHA 0.2f

typedef __bf16 bf16x8 __attribute__((ext_vector_type(8)));
typedef float floatx4 __attribute__((ext_vector_type(4)));
typedef uint16_t u16x8 __attribute__((ext_vector_type(8)));

__device__ __forceinline__ float b2f(uint16_t u){
    union { float f; uint32_t i; } x; x.i = ((uint32_t)u) << 16; return x.f;
}
__device__ __forceinline__ uint16_t f2b(float f){
    union { float f; uint32_t i; } x; x.f = f;
    uint32_t r = x.i + 0x7FFFu + ((x.i >> 16) & 1u);
    return (uint16_t)(r >> 16);
}
__device__ __forceinline__ void cvt_split8(const float* __restrict__ s, bf16x8& hv, bf16x8& lv){
    union { u16x8 u; bf16x8 b; } H, L;
    #pragma unroll
    for (int j = 0; j < 8; j++){
        uint16_t hb = f2b(s[j]);
        H.u[j] = hb;
        L.u[j] = f2b(s[j] - b2f(hb));
    }
    hv = H.b; lv = L.b;
}

// ================= Kernel A =================
// blocks [0,384):     gemm1: Wh1b = bf16(x @ W_head) + fused f1/f2  (b = bx*4 + h)
// blocks [384,432):   Wo prep -> Woth/Wotl [48,256] bf16 split transposed+padded
// block  432:         zero f1o/f2o
// blocks [433,6577):  adj row scan -> CSR neighbor lists (nontemporal, 6-deep MLP)
// gemm1 blocks dispatched first so their MFMA/VALU work overlaps the
// memory-bound adj scan (separate pipes co-schedule; m114).
__global__ void k_A(const float* __restrict__ adj, const float* __restrict__ x,
                    const float* __restrict__ W, const float* __restrict__ Wo,
                    const float* __restrict__ a1, const float* __restrict__ a2,
                    int* __restrict__ cnt, int* __restrict__ idxbuf,
                    uint16_t* __restrict__ Woth, uint16_t* __restrict__ Wotl,
                    uint16_t* __restrict__ Wh1b, float* __restrict__ f1,
                    float* __restrict__ f2, float* __restrict__ f1o,
                    float* __restrict__ f2o){
    int b = blockIdx.x, t = threadIdx.x;
    if (b < 384){
        // ---- gemm1 ----
        __shared__ float sred[2][2][64];
        int w = t >> 6, l = t & 63;
        int bx = b >> 2, h = b & 3;
        int m = l & 15, q = l >> 4;
        int rt0 = bx * 4 + (w & 1) * 2;           // row tile (16-row units)
        int ctl = (w >> 1) * 2;                   // local col tile within head
        const float* pa0 = x + (size_t)(rt0 * 16 + m) * F_IN + q * 8;
        const float* pa1 = pa0 + 16 * F_IN;
        // W[h][k][f]: base for this wave's B fragments
        const float* pb = W + h * 32768 + q * 8 * 64 + ctl * 16 + m;
        floatx4 acc[2][2] = {};
        for (int kc = 0; kc < 16; kc++){
            float av0[8], av1[8], bv0[8], bv1[8];
            *reinterpret_cast<float4*>(av0)     = *reinterpret_cast<const float4*>(pa0 + kc * 32);
            *reinterpret_cast<float4*>(av0 + 4) = *reinterpret_cast<const float4*>(pa0 + kc * 32 + 4);
            *reinterpret_cast<float4*>(av1)     = *reinterpret_cast<const float4*>(pa1 + kc * 32);
            *reinterpret_cast<float4*>(av1 + 4) = *reinterpret_cast<const float4*>(pa1 + kc * 32 + 4);
            const float* pbk = pb + kc * 2048;
            #pragma unroll
            for (int j = 0; j < 8; j++){
                bv0[j] = pbk[j * 64];
                bv1[j] = pbk[j * 64 + 16];
            }
            bf16x8 a0h, a0l, a1h_, a1l_, b0h, b0l, b1h, b1l;
            cvt_split8(av0, a0h, a0l);
            cvt_split8(av1, a1h_, a1l_);
            cvt_split8(bv0, b0h, b0l);
            cvt_split8(bv1, b1h, b1l);
            acc[0][0] = __builtin_amdgcn_mfma_f32_16x16x32_bf16(a0h, b0l, acc[0][0], 0, 0, 0);
            acc[0][0] = __builtin_amdgcn_mfma_f32_16x16x32_bf16(a0l, b0h, acc[0][0], 0, 0, 0);
            acc[0][0] = __builtin_amdgcn_mfma_f32_16x16x32_bf16(a0h, b0h, acc[0][0], 0, 0, 0);
            acc[0][1] = __builtin_amdgcn_mfma_f32_16x16x32_bf16(a0h, b1l, acc[0][1], 0, 0, 0);
            acc[0][1] = __builtin_amdgcn_mfma_f32_16x16x32_bf16(a0l, b1h, acc[0][1], 0, 0, 0);
            acc[0][1] = __builtin_amdgcn_mfma_f32_16x16x32_bf16(a0h, b1h, acc[0][1], 0, 0, 0);
            acc[1][0] = __builtin_amdgcn_mfma_f32_16x16x32_bf16(a1h_, b0l, acc[1][0], 0, 0, 0);
            acc[1][0] = __builtin_amdgcn_mfma_f32_16x16x32_bf16(a1l_, b0h, acc[1][0], 0, 0, 0);
            acc[1][0] = __builtin_amdgcn_mfma_f32_16x16x32_bf16(a1h_, b0h, acc[1][0], 0, 0, 0);
            acc[1][1] = __builtin_amdgcn_mfma_f32_16x16x32_bf16(a1h_, b1l, acc[1][1], 0, 0, 0);
            acc[1][1] = __builtin_amdgcn_mfma_f32_16x16x32_bf16(a1l_, b1h, acc[1][1], 0, 0, 0);
            acc[1][1] = __builtin_amdgcn_mfma_f32_16x16x32_bf16(a1h_, b1h, acc[1][1], 0, 0, 0);
        }
        // write bf16 Wh1b
        #pragma unroll
        for (int fr = 0; fr < 2; fr++){
            #pragma unroll
            for (int fc = 0; fc < 2; fc++){
                int col = h * 64 + (ctl + fc) * 16 + m;
                int rowb = (rt0 + fr) * 16 + q * 4;
                #pragma unroll
                for (int r = 0; r < 4; r++)
                    Wh1b[(size_t)(rowb + r) * HF + col] = f2b(acc[fr][fc][r]);
            }
        }
        // fused f1/f2 (exact fp32 path)
        float a1v0 = a1[h * FH + (ctl + 0) * 16 + m];
        float a1v1 = a1[h * FH + (ctl + 1) * 16 + m];
        float a2v0 = a2[h * FH + (ctl + 0) * 16 + m];
        float a2v1 = a2[h * FH + (ctl + 1) * 16 + m];
        #pragma unroll
        for (int fr = 0; fr < 2; fr++){
            #pragma unroll
            for (int r = 0; r < 4; r++){
                float s1 = acc[fr][0][r] * a1v0 + acc[fr][1][r] * a1v1;
                float s2 = acc[fr][0][r] * a2v0 + acc[fr][1][r] * a2v1;
                #pragma unroll
                for (int off = 1; off < 16; off <<= 1){
                    s1 += __shfl_xor(s1, off);
                    s2 += __shfl_xor(s2, off);
                }
                if (m == 0){
                    int lr = ((w & 1) * 2 + fr) * 16 + q * 4 + r;
                    sred[w >> 1][0][lr] = s1;
                    sred[w >> 1][1][lr] = s2;
                }
            }
        }
        __syncthreads();
        if (t < 64){
            int n = bx * 64 + t;
            f1[h * N_NODES + n] = sred[0][0][t] + sred[1][0][t];
            f2[h * N_NODES + n] = sred[0][1][t] + sred[1][1][t];
        }
    } else if (b < 432){
        int T = (b - 384) * 256 + t;          // 0..12287
        int c = T >> 8, k = T & 255;          // c = class (padded to 48), k
        float v = (c < NCLS) ? Wo[k * NCLS + c] : 0.f;
        uint16_t hi = f2b(v);
        Woth[c * HF + k] = hi;
        Wotl[c * HF + k] = f2b(v - b2f(hi));
    } else if (b == 432){
        for (int i = t; i < N_NODES; i += 256){ f1o[i] = 0.f; f2o[i] = 0.f; }
    } else {
        // ---- adj row scan (nontemporal, 6-deep MLP) ----
        __shared__ int scnt;
        int i = b - 433;
        if (t == 0) scnt = 0;
        __syncthreads();
        const floatx4* row = reinterpret_cast<const floatx4*>(adj + (size_t)i * N_NODES);
        int* out = idxbuf + (size_t)i * CAP;
        floatx4 v[6];                         // 1536/256 = 6 exact
        #pragma unroll
        for (int u = 0; u < 6; u++)
            v[u] = __builtin_nontemporal_load(row + t + u * 256);
        #pragma unroll
        for (int u = 0; u < 6; u++){
            int j0 = (t + u * 256) * 4;
            if (v[u][0] != 0.f){ int p = atomicAdd(&scnt, 1); if (p < CAP) out[p] = j0;     }
            if (v[u][1] != 0.f){ int p = atomicAdd(&scnt, 1); if (p < CAP) out[p] = j0 + 1; }
            if (v[u][2] != 0.f){ int p = atomicAdd(&scnt, 1); if (p < CAP) out[p] = j0 + 2; }
            if (v[u][3] != 0.f){ int p = atomicAdd(&scnt, 1); if (p < CAP) out[p] = j0 + 3; }
        }
        __syncthreads();
        if (t == 0) cnt[i] = scnt < CAP ? scnt : CAP;
    }
}

// ================= Kernel B: layer-1 sparse attention + ELU -> hcat split bf16 =============
// grid 6144, block 256 (wave h = head h)
__global__ void k_attn1(const int* __restrict__ cnt, const int* __restrict__ idxbuf,
                        const uint16_t* __restrict__ Wh1b, const float* __restrict__ f1,
                        const float* __restrict__ f2,
                        uint16_t* __restrict__ hch, uint16_t* __restrict__ hcl){
    int i = blockIdx.x, h = threadIdx.x >> 6, l = threadIdx.x & 63;
    int c = cnt[i];
    __shared__ int   sidx[CAP];
    __shared__ float sp[NHEAD][CAP];
    const int* src = idxbuf + (size_t)i * CAP;
    for (int e = threadIdx.x; e < c; e += 256) sidx[e] = src[e];
    __syncthreads();
    float f1i = f1[h * N_NODES + i];
    const float* f2h = f2 + h * N_NODES;
    float mx = -1e30f;
    for (int e = l; e < c; e += 64){
        float s = f1i + f2h[sidx[e]];
        s = s > 0.f ? s : LRELU_ALPHA * s;
        sp[h][e] = s;
        mx = fmaxf(mx, s);
    }
    for (int off = 32; off; off >>= 1) mx = fmaxf(mx, __shfl_xor(mx, off));
    float ssum = 0.f;
    for (int e = l; e < c; e += 64){
        float p = __expf(sp[h][e] - mx);
        sp[h][e] = p;
        ssum += p;
    }
    for (int off = 32; off; off >>= 1) ssum += __shfl_xor(ssum, off);
    float inv = 1.f / ssum;
    float acc = 0.f;
    const uint16_t* whb = Wh1b + h * FH + l;
    int e = 0;
    for (; e + 4 <= c; e += 4){
        int j0 = sidx[e], j1 = sidx[e+1], j2 = sidx[e+2], j3 = sidx[e+3];
        float v0 = b2f(whb[(size_t)j0 * HF]);
        float v1 = b2f(whb[(size_t)j1 * HF]);
        float v2 = b2f(whb[(size_t)j2 * HF]);
        float v3 = b2f(whb[(size_t)j3 * HF]);
        acc += sp[h][e]*v0 + sp[h][e+1]*v1 + sp[h][e+2]*v2 + sp[h][e+3]*v3;
    }
    for (; e < c; e++)
        acc += sp[h][e] * b2f(whb[(size_t)sidx[e] * HF]);
    acc *= inv;
    float v = acc > 0.f ? acc : __expf(acc) - 1.f;   // ELU
    uint16_t hi = f2b(v);
    uint16_t lo = f2b(v - b2f(hi));
    size_t o = (size_t)i * HF + h * FH + l;
    hch[o] = hi;
    hcl[o] = lo;
}

// ========== Kernel C: Wh2 = hcat @ Wo (split-bf16 MFMA) + fused f1o/f2o (atomics) ==========
// grid (192,3), block 128 = 2 waves; wave tile 16 rows x 16 cols.
__global__ void k_gemm2(const uint16_t* __restrict__ hch, const uint16_t* __restrict__ hcl,
                        const uint16_t* __restrict__ Woth, const uint16_t* __restrict__ Wotl,
                        const float* __restrict__ ao1, const float* __restrict__ ao2,
                        float* __restrict__ Wh2, float* __restrict__ f1o,
                        float* __restrict__ f2o){
    int w = threadIdx.x >> 6, l = threadIdx.x & 63;
    int r0 = blockIdx.x * 32 + w * 16;
    int c0 = blockIdx.y * 16;
    int m = l & 15, q = l >> 4;
    const uint16_t* pah = hch  + (size_t)(r0 + m) * HF + q * 8;
    const uint16_t* pal = hcl  + (size_t)(r0 + m) * HF + q * 8;
    const uint16_t* pbh = Woth + (size_t)(c0 + m) * HF + q * 8;
    const uint16_t* pbl = Wotl + (size_t)(c0 + m) * HF + q * 8;
    floatx4 acc = {};
    for (int k0 = 0; k0 < HF; k0 += 32){
        bf16x8 ah = *reinterpret_cast<const bf16x8*>(pah + k0);
        bf16x8 al = *reinterpret_cast<const bf16x8*>(pal + k0);
        bf16x8 bh = *reinterpret_cast<const bf16x8*>(pbh + k0);
        bf16x8 bl = *reinterpret_cast<const bf16x8*>(pbl + k0);
        acc = __builtin_amdgcn_mfma_f32_16x16x32_bf16(ah, bl, acc, 0, 0, 0);
        acc = __builtin_amdgcn_mfma_f32_16x16x32_bf16(al, bh, acc, 0, 0, 0);
        acc = __builtin_amdgcn_mfma_f32_16x16x32_bf16(ah, bh, acc, 0, 0, 0);
    }
    int col = c0 + m;
    bool valid = col < NCLS;
    if (valid){
        int rowb = r0 + q * 4;
        #pragma unroll
        for (int r = 0; r < 4; r++)
            Wh2[(size_t)(rowb + r) * NCLS + col] = acc[r];
    }
    float w1 = valid ? ao1[col] : 0.f;
    float w2 = valid ? ao2[col] : 0.f;
    #pragma unroll
    for (int r = 0; r < 4; r++){
        float s1 = acc[r] * w1;
        float s2 = acc[r] * w2;
        #pragma unroll
        for (int off = 1; off < 16; off <<= 1){
            s1 += __shfl_xor(s1, off);
            s2 += __shfl_xor(s2, off);
        }
        if (m == 0){
            atomicAdd(f1o + r0 + q * 4 + r, s1);
            atomicAdd(f2o + r0 + q * 4 + r, s2);
        }
    }
}

// ========== Kernel D: layer-2 attention + ELU + log_softmax -> out fp32 ==========
// grid 1536, block 256: one wave per node, 4 nodes/block (wave-synchronous).
__global__ void k_attn2(const int* __restrict__ cnt, const int* __restrict__ idxbuf,
                        const float* __restrict__ Wh2, const float* __restrict__ f1o,
                        const float* __restrict__ f2o, float* __restrict__ out){
    int t = threadIdx.x;
    int w = t >> 6, l = t & 63;
    int i = blockIdx.x * 4 + w;
    int c = cnt[i];
    __shared__ int   sidxD[4][CAP];
    __shared__ float spD[4][CAP];
    int*   sidx = sidxD[w];
    float* sp   = spD[w];
    const int* src = idxbuf + (size_t)i * CAP;
    for (int e = l; e < c; e += 64) sidx[e] = src[e];
    float f1i = f1o[i];
    float mx = -1e30f;
    for (int e = l; e < c; e += 64){
        float s = f1i + f2o[sidx[e]];
        s = s > 0.f ? s : LRELU_ALPHA * s;
        sp[e] = s;
        mx = fmaxf(mx, s);
    }
    for (int off = 32; off; off >>= 1) mx = fmaxf(mx, __shfl_xor(mx, off));
    float ssum = 0.f;
    for (int e = l; e < c; e += 64){
        float p = __expf(sp[e] - mx);
        sp[e] = p;
        ssum += p;
    }
    for (int off = 32; off; off >>= 1) ssum += __shfl_xor(ssum, off);
    float inv = 1.f / ssum;
    float acc = 0.f;
    if (l < NCLS){
        const float* wb = Wh2 + l;
        int e = 0;
        for (; e + 4 <= c; e += 4){
            int j0 = sidx[e], j1 = sidx[e+1], j2 = sidx[e+2], j3 = sidx[e+3];
            float v0 = wb[(size_t)j0 * NCLS];
            float v1 = wb[(size_t)j1 * NCLS];
            float v2 = wb[(size_t)j2 * NCLS];
            float v3 = wb[(size_t)j3 * NCLS];
            acc += sp[e]*v0 + sp[e+1]*v1 + sp[e+2]*v2 + sp[e+3]*v3;
        }
        for (; e < c; e++)
            acc += sp[e] * wb[(size_t)sidx[e] * NCLS];
        acc *= inv;
    }
    float o = (l < NCLS) ? (acc > 0.f ? acc : __expf(acc) - 1.f) : -1e30f;
    float m2 = o;
    for (int off = 32; off; off >>= 1) m2 = fmaxf(m2, __shfl_xor(m2, off));
    float ex = (l < NCLS) ? __expf(o - m2) : 0.f;
    for (int off = 32; off; off >>= 1) ex += __shfl_xor(ex, off);
    float res = o - m2 - logf(ex);
    if (l < NCLS) out[(size_t)i * NCLS + l] = res;
}

extern "C" void kernel_launch(void* const* d_in, const int* in_sizes, int n_in,
                              void* d_out, int out_size, void* d_ws, size_t ws_size,
                              hipStream_t stream) {
    const float* x   = (const float*)d_in[0];
    const float* adj = (const float*)d_in[1];
    const float* W   = (const float*)d_in[2];
    const float* a1  = (const float*)d_in[3];
    const float* a2  = (const float*)d_in[4];
    const float* Wo  = (const float*)d_in[5];
    const float* ao1 = (const float*)d_in[6];
    const float* ao2 = (const float*)d_in[7];
    float* out = (float*)d_out;

    char* ws = (char*)d_ws;
    int*      nbr_cnt = (int*)     (ws + 0);          //     24,576 B
    int*      nbr_idx = (int*)     (ws + 24576);      //  4,718,592 B
    uint16_t* Woth    = (uint16_t*)(ws + 4743168);    //     24,576 B
    uint16_t* Wotl    = (uint16_t*)(ws + 4767744);    //     24,576 B
    uint16_t* Wh1b    = (uint16_t*)(ws + 4792320);    //  3,145,728 B
    float*    f1      = (float*)   (ws + 7938048);    //     98,304 B
    float*    f2      = (float*)   (ws + 8036352);    //     98,304 B
    uint16_t* hch     = (uint16_t*)(ws + 8134656);    //  3,145,728 B
    uint16_t* hcl     = (uint16_t*)(ws + 11280384);   //  3,145,728 B
    float*    Wh2     = (float*)   (ws + 14426112);   //    983,040 B
    float*    f1o     = (float*)   (ws + 15409152);   //     24,576 B
    float*    f2o     = (float*)   (ws + 15433728);   //     24,576 B -> total ~15.5 MB

    hipLaunchKernelGGL(k_A,     dim3(6577),   dim3(256), 0, stream, adj, x, W, Wo, a1, a2,
                       nbr_cnt, nbr_idx, Woth, Wotl, Wh1b, f1, f2, f1o, f2o);
    hipLaunchKernelGGL(k_attn1, dim3(6144),   dim3(256), 0, stream, nbr_cnt, nbr_idx,
                       Wh1b, f1, f2, hch, hcl);
    hipLaunchKernelGGL(k_gemm2, dim3(192, 3), dim3(128), 0, stream, hch, hcl, Woth, Wotl,
                       ao1, ao2, Wh2, f1o, f2o);
    hipLaunchKernelGGL(k_attn2, dim3(1536),   dim3(256), 0, stream, nbr_cnt, nbr_idx,
                       Wh2, f1o, f2o, out);
}